// Round 1
// baseline (114.592 us; speedup 1.0000x reference)
//
#include <hip/hip_runtime.h>

// Adversarial embedding perturbation:
//   L[t]   = argmax_b of gumbel(key=42) masked by dpadder[t,b] != 1
//   A      = emb, with A[t, L[t], :] = emb[t, L[t], :] * (1 + eps/||row||)
//   out    = [A (2048*32*1024 f32), L (2048, written as f32)]
//
// Gumbel argmax == argmax over raw threefry bits>>9 (monotone map), so we
// reproduce JAX's threefry2x32 bit-exactly and skip the float log chain.
//
// THREEFRY VARIANT: jax_threefry_partitionable=True (modern JAX default):
//   per-element counter = flat uint64 index -> (hi=0, lo=i), key=(0,42),
//   output bits = x0 ^ x1 after 20 rounds.
// If this round fails with absmax ~5: switch to the ORIGINAL scheme
//   (iota(uint32, 65536) split in halves -> pairs (i, i+32768), out = x0 for
//   first half / x1 for second half).

#define EPSILON 0.05f

#define TLEN 2048
#define BZ 32
#define EMB 1024

#define TF_R(r) { x0 += x1; x1 = (x1 << (r)) | (x1 >> (32 - (r))); x1 ^= x0; }

__device__ inline unsigned int threefry_bits32(unsigned int idx) {
  const unsigned int k0 = 0u;           // hi 32 of seed 42
  const unsigned int k1 = 42u;          // lo 32 of seed 42
  const unsigned int k2 = 0x1BD11BDAu ^ k0 ^ k1;
  unsigned int x0 = 0u  + k0;           // counter hi = 0 (idx < 2^32)
  unsigned int x1 = idx + k1;           // counter lo = flat index
  TF_R(13) TF_R(15) TF_R(26) TF_R(6)
  x0 += k1; x1 += k2 + 1u;
  TF_R(17) TF_R(29) TF_R(16) TF_R(24)
  x0 += k2; x1 += k0 + 2u;
  TF_R(13) TF_R(15) TF_R(26) TF_R(6)
  x0 += k0; x1 += k1 + 3u;
  TF_R(17) TF_R(29) TF_R(16) TF_R(24)
  x0 += k1; x1 += k2 + 4u;
  TF_R(13) TF_R(15) TF_R(26) TF_R(6)
  x0 += k2; x1 += k0 + 5u;
  return x0 ^ x1;                        // 32-bit partitionable output
}

// One block (256 thr = 4 waves) per row t:
//   wave 0 lanes 0..31: threefry bits + mask -> packed argmax (first-index
//   tie-break: larger key wins, ties -> smaller lane via (63-lane) field).
//   Then all 4 waves: sum-of-squares over emb[t, L, 0:1024] -> scale.
__global__ __launch_bounds__(256) void select_rows(
    const float* __restrict__ emb, const int* __restrict__ dpad,
    int* __restrict__ wsL, float* __restrict__ wsScale,
    float* __restrict__ outL)
{
  const int t = blockIdx.x;
  const int tid = threadIdx.x;
  __shared__ int sL;
  __shared__ float swave[4];

  if (tid < 64) {
    unsigned long long packed = 0ull;
    if (tid < 32) {
      unsigned int bits = threefry_bits32((unsigned int)(t * BZ + tid));
      unsigned int key = bits >> 9;   // top 23 bits == uniform mantissa order
      bool valid = (dpad[t * BZ + tid] != 1);
      if (valid)
        packed = (((unsigned long long)(key + 1u)) << 6) |
                 (unsigned long long)(63 - tid);
    }
    #pragma unroll
    for (int off = 32; off > 0; off >>= 1) {
      unsigned long long other = __shfl_xor(packed, off, 64);
      if (other > packed) packed = other;
    }
    if (tid == 0) {
      // all-invalid row: argmax of all -inf == 0
      sL = (packed == 0ull) ? 0 : (63 - (int)(packed & 63ull));
    }
  }
  __syncthreads();
  const int L = sL;

  const float4* row = (const float4*)(emb + ((size_t)t * BZ + L) * EMB);
  float4 v = row[tid];
  float ss = v.x * v.x + v.y * v.y + v.z * v.z + v.w * v.w;
  #pragma unroll
  for (int off = 32; off > 0; off >>= 1) ss += __shfl_xor(ss, off, 64);
  if ((tid & 63) == 0) swave[tid >> 6] = ss;
  __syncthreads();
  if (tid == 0) {
    float norm = sqrtf(swave[0] + swave[1] + swave[2] + swave[3]);
    wsL[t] = L;
    wsScale[t] = 1.0f + EPSILON / norm;
    outL[t] = (float)L;
  }
}

// Overwrite the 2048 selected rows of the (already-copied) output:
//   out[t, L[t], :] = emb[t, L[t], :] * scale[t]
__global__ __launch_bounds__(256) void fixup_rows(
    const float* __restrict__ emb, const int* __restrict__ wsL,
    const float* __restrict__ wsScale, float* __restrict__ out)
{
  const int t = blockIdx.x;
  const int L = wsL[t];
  const float s = wsScale[t];
  const size_t base = ((size_t)t * BZ + L) * EMB;
  const float4* src = (const float4*)(emb + base);
  float4* dst = (float4*)(out + base);
  float4 v = src[threadIdx.x];
  v.x *= s; v.y *= s; v.z *= s; v.w *= s;
  dst[threadIdx.x] = v;
}

extern "C" void kernel_launch(void* const* d_in, const int* in_sizes, int n_in,
                              void* d_out, int out_size, void* d_ws, size_t ws_size,
                              hipStream_t stream) {
  const float* emb = (const float*)d_in[0];
  // d_in[1] (data, int64) is mathematically unused by the reference.
  const int* dpad = (const int*)d_in[2];
  float* out = (float*)d_out;

  const size_t Asz = (size_t)TLEN * BZ * EMB;  // 67,108,864 floats
  int* wsL = (int*)d_ws;
  float* wsScale = (float*)((char*)d_ws + TLEN * sizeof(int));

  // 1) pick rows + norms (independent of the copy)
  select_rows<<<TLEN, 256, 0, stream>>>(emb, dpad, wsL, wsScale, out + Asz);
  // 2) bulk copy A = emb (256 MiB, HBM-bound; this is the roofline term)
  hipMemcpyAsync(out, emb, Asz * sizeof(float), hipMemcpyDeviceToDevice, stream);
  // 3) rewrite the 2048 selected rows scaled
  fixup_rows<<<TLEN, 256, 0, stream>>>(emb, wsL, wsScale, out);
}

// Round 3
// 92.212 us; speedup vs baseline: 1.2427x; 1.2427x over previous
//
#include <hip/hip_runtime.h>

// Adversarial embedding perturbation, fused:
//   L[t]   = argmax_b of gumbel(key=42) masked by dpadder[t,b] != 1
//   A      = emb, with A[t, L[t], :] = emb[t, L[t], :] * (1 + eps/||row||)
//   out    = [A (2048*32*1024 f32), L (2048, written as f32)]
//
// Gumbel argmax == argmax over raw threefry bits>>9 (monotone map) -> we
// reproduce JAX threefry2x32 (partitionable variant, verified round 1)
// bit-exactly and skip the float log chain.
//
// Round-3: same as round-2 plan, but use clang ext_vector_type float4 for
// __builtin_nontemporal_* (HIP_vector_type float4 is rejected by the builtin).

#define EPSILON 0.05f

#define TLEN 2048
#define BZ 32
#define EMB 1024
#define ROWS (TLEN * BZ)          // 65536 rows of 1024 floats (4 KiB)

typedef float f32x4 __attribute__((ext_vector_type(4)));

#define TF_R(r) { x0 += x1; x1 = (x1 << (r)) | (x1 >> (32 - (r))); x1 ^= x0; }

__device__ inline unsigned int threefry_bits32(unsigned int idx) {
  const unsigned int k0 = 0u;           // hi 32 of seed 42
  const unsigned int k1 = 42u;          // lo 32 of seed 42
  const unsigned int k2 = 0x1BD11BDAu ^ k0 ^ k1;
  unsigned int x0 = 0u  + k0;           // counter hi = 0 (idx < 2^32)
  unsigned int x1 = idx + k1;           // counter lo = flat index
  TF_R(13) TF_R(15) TF_R(26) TF_R(6)
  x0 += k1; x1 += k2 + 1u;
  TF_R(17) TF_R(29) TF_R(16) TF_R(24)
  x0 += k2; x1 += k0 + 2u;
  TF_R(13) TF_R(15) TF_R(26) TF_R(6)
  x0 += k0; x1 += k1 + 3u;
  TF_R(17) TF_R(29) TF_R(16) TF_R(24)
  x0 += k1; x1 += k2 + 4u;
  TF_R(13) TF_R(15) TF_R(26) TF_R(6)
  x0 += k2; x1 += k0 + 5u;
  return x0 ^ x1;                        // partitionable output = x0 ^ x1
}

// One wave per row t (4 waves/block). Lanes 0..31: threefry bits + mask ->
// packed argmax (larger key wins; ties -> smaller lane via (63-lane) field).
__global__ __launch_bounds__(256) void select_rows(
    const int* __restrict__ dpad, int* __restrict__ wsL,
    float* __restrict__ outL)
{
  const int t = blockIdx.x * 4 + (threadIdx.x >> 6);
  const int lane = threadIdx.x & 63;

  unsigned long long packed = 0ull;
  if (lane < 32) {
    unsigned int bits = threefry_bits32((unsigned int)(t * BZ + lane));
    unsigned int key = bits >> 9;   // top 23 bits == uniform mantissa order
    if (dpad[t * BZ + lane] != 1)
      packed = (((unsigned long long)(key + 1u)) << 6) |
               (unsigned long long)(63 - lane);
  }
  #pragma unroll
  for (int off = 32; off > 0; off >>= 1) {
    unsigned long long other = __shfl_xor(packed, off, 64);
    if (other > packed) packed = other;
  }
  if (lane == 0) {
    int L = (packed == 0ull) ? 0 : (63 - (int)(packed & 63ull));
    wsL[t] = L;
    outL[t] = (float)L;
  }
}

// Fused copy+scale: one wave per 4 KiB row (4 rows per 256-thread block).
// Each lane holds 4 float4 (16 floats). If this wave's row is the selected
// one for its t, wave-reduce the sum of squares and scale before storing.
// The (b == L[t]) branch is wave-uniform -> no divergence.
__global__ __launch_bounds__(256) void copy_scale(
    const float* __restrict__ emb, const int* __restrict__ wsL,
    float* __restrict__ out)
{
  const int r = blockIdx.x * 4 + (threadIdx.x >> 6);  // row in [0, 65536)
  const int lane = threadIdx.x & 63;
  const int t = r >> 5;
  const int b = r & 31;

  const f32x4* src = (const f32x4*)(emb + ((size_t)r << 10));
  f32x4* dst = (f32x4*)(out + ((size_t)r << 10));

  f32x4 v0 = __builtin_nontemporal_load(src + lane);
  f32x4 v1 = __builtin_nontemporal_load(src + lane + 64);
  f32x4 v2 = __builtin_nontemporal_load(src + lane + 128);
  f32x4 v3 = __builtin_nontemporal_load(src + lane + 192);

  if (b == wsL[t]) {                       // wave-uniform
    f32x4 sq = v0 * v0 + v1 * v1 + v2 * v2 + v3 * v3;
    float ss = sq.x + sq.y + sq.z + sq.w;
    #pragma unroll
    for (int off = 32; off > 0; off >>= 1) ss += __shfl_xor(ss, off, 64);
    const float s = 1.0f + EPSILON / sqrtf(ss);
    v0 *= s; v1 *= s; v2 *= s; v3 *= s;
  }

  __builtin_nontemporal_store(v0, dst + lane);
  __builtin_nontemporal_store(v1, dst + lane + 64);
  __builtin_nontemporal_store(v2, dst + lane + 128);
  __builtin_nontemporal_store(v3, dst + lane + 192);
}

extern "C" void kernel_launch(void* const* d_in, const int* in_sizes, int n_in,
                              void* d_out, int out_size, void* d_ws, size_t ws_size,
                              hipStream_t stream) {
  const float* emb = (const float*)d_in[0];
  // d_in[1] (data, int64) is mathematically unused by the reference.
  const int* dpad = (const int*)d_in[2];
  float* out = (float*)d_out;

  const size_t Asz = (size_t)TLEN * BZ * EMB;  // 67,108,864 floats
  int* wsL = (int*)d_ws;

  // 1) pick rows (threefry argmax only; no emb traffic)
  select_rows<<<TLEN / 4, 256, 0, stream>>>(dpad, wsL, out + Asz);
  // 2) fused copy + norm + scale: exactly 256 MiB read + 256 MiB write
  copy_scale<<<ROWS / 4, 256, 0, stream>>>(emb, wsL, out);
}

// Round 4
// 89.300 us; speedup vs baseline: 1.2832x; 1.0326x over previous
//
#include <hip/hip_runtime.h>

// Adversarial embedding perturbation — single fused kernel:
//   L[t]   = argmax_b of gumbel(key=42) masked by dpadder[t,b] != 1
//   A      = emb, with A[t, L[t], :] = emb[t, L[t], :] * (1 + eps/||row||)
//   out    = [A (2048*32*1024 f32), L (2048, written as f32)]
//
// Gumbel argmax == argmax over raw threefry bits>>9 (monotone map) -> we
// reproduce JAX threefry2x32 (partitionable variant, verified round 1)
// bit-exactly and skip the float log chain.
//
// Round-4: fuse selection INTO the copy kernel. The copy is memory-bound
// (VALUBusy ~5%), so each wave redundantly recomputes its own t's 32-hash
// argmax while its 16 nontemporal loads are in flight — removes the
// select_rows dispatch and its serialization (~4-6 us). Exactly 256 MiB
// read + 256 MiB write of emb traffic; dpad re-reads hit L2 (256 KB unique).

#define EPSILON 0.05f

#define TLEN 2048
#define BZ 32
#define EMB 1024
#define ROWS (TLEN * BZ)          // 65536 rows of 1024 floats (4 KiB)

typedef float f32x4 __attribute__((ext_vector_type(4)));

#define TF_R(r) { x0 += x1; x1 = (x1 << (r)) | (x1 >> (32 - (r))); x1 ^= x0; }

__device__ inline unsigned int threefry_bits32(unsigned int idx) {
  const unsigned int k0 = 0u;           // hi 32 of seed 42
  const unsigned int k1 = 42u;          // lo 32 of seed 42
  const unsigned int k2 = 0x1BD11BDAu ^ k0 ^ k1;
  unsigned int x0 = 0u  + k0;           // counter hi = 0 (idx < 2^32)
  unsigned int x1 = idx + k1;           // counter lo = flat index
  TF_R(13) TF_R(15) TF_R(26) TF_R(6)
  x0 += k1; x1 += k2 + 1u;
  TF_R(17) TF_R(29) TF_R(16) TF_R(24)
  x0 += k2; x1 += k0 + 2u;
  TF_R(13) TF_R(15) TF_R(26) TF_R(6)
  x0 += k0; x1 += k1 + 3u;
  TF_R(17) TF_R(29) TF_R(16) TF_R(24)
  x0 += k1; x1 += k2 + 4u;
  TF_R(13) TF_R(15) TF_R(26) TF_R(6)
  x0 += k2; x1 += k0 + 5u;
  return x0 ^ x1;                        // partitionable output = x0 ^ x1
}

// One wave per 4 KiB row (4 rows / 256-thread block). Each lane holds 4
// float4. While the loads are in flight, lanes 0..31 recompute the wave's
// t-argmax (threefry bits + dpad mask; larger key wins, ties -> smaller
// lane). The wave whose b == L[t] wave-reduces the sum of squares, scales
// before storing, and writes outL[t]. All branches are wave-uniform.
__global__ __launch_bounds__(256) void copy_scale_select(
    const float* __restrict__ emb, const int* __restrict__ dpad,
    float* __restrict__ out, float* __restrict__ outL)
{
  const int r = blockIdx.x * 4 + (threadIdx.x >> 6);  // row in [0, 65536)
  const int lane = threadIdx.x & 63;
  const int t = r >> 5;
  const int b = r & 31;

  const f32x4* src = (const f32x4*)(emb + ((size_t)r << 10));
  f32x4* dst = (f32x4*)(out + ((size_t)r << 10));

  f32x4 v0 = __builtin_nontemporal_load(src + lane);
  f32x4 v1 = __builtin_nontemporal_load(src + lane + 64);
  f32x4 v2 = __builtin_nontemporal_load(src + lane + 128);
  f32x4 v3 = __builtin_nontemporal_load(src + lane + 192);

  // Redundant per-wave argmax for this wave's t (hidden under the loads).
  unsigned long long packed = 0ull;
  if (lane < 32) {
    unsigned int bits = threefry_bits32((unsigned int)(t * BZ + lane));
    unsigned int key = bits >> 9;   // top 23 bits == uniform mantissa order
    if (dpad[t * BZ + lane] != 1)
      packed = (((unsigned long long)(key + 1u)) << 6) |
               (unsigned long long)(63 - lane);
  }
  #pragma unroll
  for (int off = 32; off > 0; off >>= 1) {
    unsigned long long other = __shfl_xor(packed, off, 64);
    if (other > packed) packed = other;
  }
  const int L = (packed == 0ull) ? 0 : (63 - (int)(packed & 63ull));

  if (b == L) {                            // wave-uniform
    f32x4 sq = v0 * v0 + v1 * v1 + v2 * v2 + v3 * v3;
    float ss = sq.x + sq.y + sq.z + sq.w;
    #pragma unroll
    for (int off = 32; off > 0; off >>= 1) ss += __shfl_xor(ss, off, 64);
    const float s = 1.0f + EPSILON / sqrtf(ss);
    v0 *= s; v1 *= s; v2 *= s; v3 *= s;
    if (lane == 0) outL[t] = (float)L;
  }

  __builtin_nontemporal_store(v0, dst + lane);
  __builtin_nontemporal_store(v1, dst + lane + 64);
  __builtin_nontemporal_store(v2, dst + lane + 128);
  __builtin_nontemporal_store(v3, dst + lane + 192);
}

extern "C" void kernel_launch(void* const* d_in, const int* in_sizes, int n_in,
                              void* d_out, int out_size, void* d_ws, size_t ws_size,
                              hipStream_t stream) {
  const float* emb = (const float*)d_in[0];
  // d_in[1] (data, int64) is mathematically unused by the reference.
  const int* dpad = (const int*)d_in[2];
  float* out = (float*)d_out;

  const size_t Asz = (size_t)TLEN * BZ * EMB;  // 67,108,864 floats

  copy_scale_select<<<ROWS / 4, 256, 0, stream>>>(emb, dpad, out, out + Asz);
}